// Round 1
// baseline (114.447 us; speedup 1.0000x reference)
//
#include <hip/hip_runtime.h>
#include <math.h>

#define BB 16
#define TT 1024
#define T1 1025
#define DD 512

// ---------------- Kernel 1: alphas = sigmoid(hidden @ w + b) ----------------
// one 64-lane wave per (b,t) row; 4 waves per 256-thread block
__global__ __launch_bounds__(256) void alpha_kernel(
    const float* __restrict__ hidden,   // [B, T, D]
    const float* __restrict__ w,        // [D]
    const float* __restrict__ bias,     // [1]
    float* __restrict__ alphas_out)     // [B, T1]  (t < T written here)
{
    int row  = blockIdx.x * 4 + (threadIdx.x >> 6);   // 0 .. B*T-1
    int lane = threadIdx.x & 63;
    const float* h = hidden + (size_t)row * DD;
    float4 x0 = *(const float4*)(h + lane * 4);
    float4 x1 = *(const float4*)(h + 256 + lane * 4);
    float4 w0 = *(const float4*)(w + lane * 4);
    float4 w1 = *(const float4*)(w + 256 + lane * 4);
    float s = x0.x * w0.x + x0.y * w0.y + x0.z * w0.z + x0.w * w0.w
            + x1.x * w1.x + x1.y * w1.y + x1.z * w1.z + x1.w * w1.w;
    #pragma unroll
    for (int off = 32; off > 0; off >>= 1) s += __shfl_down(s, off, 64);
    if (lane == 0) {
        float x = s + bias[0];
        float sig = 1.0f / (1.0f + expf(-x));
        // relu(sig * SMOOTH_FACTOR - NOISE_THRESHOLD) with SMOOTH=1, NOISE=0 == sig
        int b = row >> 10;       // / TT
        int t = row & 1023;      // % TT
        alphas_out[b * T1 + t] = sig;
    }
}

// ---------------- Kernel 2: sequential CIF scalar scan (per batch) ----------
__global__ __launch_bounds__(128) void scan_kernel(
    float* __restrict__ alphas_out,   // [B, T1]; we also write the zero tail col
    float* __restrict__ token_num,    // [B]
    float* __restrict__ cif_peak,     // [B, T1]
    float* __restrict__ cur,          // ws [B, T1]
    float* __restrict__ rem,          // ws [B, T1]
    int*   __restrict__ fire_time,    // ws [B, T1]
    int*   __restrict__ nfired)       // ws [B]
{
    int b = blockIdx.x;
    __shared__ float a_sh[T1];
    for (int t = threadIdx.x; t < TT; t += blockDim.x)
        a_sh[t] = alphas_out[b * T1 + t];
    if (threadIdx.x == 0) a_sh[TT] = 0.0f;   // tail step: appended zero alpha
    __syncthreads();
    if (threadIdx.x != 0) return;

    alphas_out[b * T1 + TT] = 0.0f;          // write the tail column of alphas output

    float integrate = 0.0f;
    double asum = 0.0;
    int cnt = 0;
    float* peak_b = cif_peak + b * T1;
    float* cur_b  = cur + b * T1;
    float* rem_b  = rem + b * T1;
    int*   ft_b   = fire_time + b * T1;
    for (int t = 0; t < T1; ++t) {
        float a = a_sh[t];
        asum += (double)a;
        float dist = 1.0f - integrate;       // dist_completion (uses OLD integrate)
        integrate = integrate + a;           // exact f32 sequential op, as reference
        bool fire = (integrate >= 1.0f);
        float c = fire ? dist : a;
        peak_b[t] = integrate;               // fires value captured pre-subtract
        cur_b[t]  = c;
        rem_b[t]  = a - c;
        if (fire) {
            ft_b[cnt] = t;
            cnt++;
            integrate -= 1.0f;
        }
    }
    nfired[b] = cnt;
    token_num[b] = (float)floor(asum);
}

// ---------------- Kernel 3: segmented weighted sums -> packed frames --------
// one block per (b, j) output row; 128 threads x float4 = 512 floats
__global__ __launch_bounds__(128) void fill_kernel(
    const float* __restrict__ hidden,     // [B, T, D]
    const float* __restrict__ cur,        // ws [B, T1]
    const float* __restrict__ rem,        // ws [B, T1]
    const int*   __restrict__ fire_time,  // ws [B, T1]
    const int*   __restrict__ nfired,     // ws [B]
    float* __restrict__ ae)               // [B, T1, D]
{
    int idx = blockIdx.x;
    int b = idx / T1;
    int j = idx % T1;
    int d = threadIdx.x * 4;
    float4* out4 = (float4*)(ae + ((size_t)b * T1 + j) * DD + d);

    int nf = nfired[b];
    if (j >= nf) {                        // unfired slot: zeros
        *out4 = make_float4(0.f, 0.f, 0.f, 0.f);
        return;
    }
    const int*   ft_b  = fire_time + b * T1;
    const float* cur_b = cur + b * T1;
    const float* hb    = hidden + (size_t)b * TT * DD + d;

    int e = ft_b[j];                      // fire time of this token (<= T-1)
    float4 acc = make_float4(0.f, 0.f, 0.f, 0.f);
    int t0;
    if (j > 0) {
        int s = ft_b[j - 1];
        float r = rem[b * T1 + s];        // remainder of previous fire
        float4 h = *(const float4*)(hb + (size_t)s * DD);
        acc.x = r * h.x; acc.y = r * h.y; acc.z = r * h.z; acc.w = r * h.w;
        t0 = s + 1;
    } else {
        t0 = 0;
    }
    for (int t = t0; t <= e; ++t) {       // uniform bounds per block -> no divergence
        float c = cur_b[t];
        float4 h = *(const float4*)(hb + (size_t)t * DD);
        acc.x += c * h.x; acc.y += c * h.y; acc.z += c * h.z; acc.w += c * h.w;
    }
    *out4 = acc;
}

extern "C" void kernel_launch(void* const* d_in, const int* in_sizes, int n_in,
                              void* d_out, int out_size, void* d_ws, size_t ws_size,
                              hipStream_t stream) {
    const float* hidden = (const float*)d_in[0];
    const float* w      = (const float*)d_in[1];
    const float* bias   = (const float*)d_in[2];

    float* out        = (float*)d_out;
    float* ae         = out;                                   // [B,T1,D]
    float* token_num  = out + (size_t)BB * T1 * DD;            // [B]
    float* alphas_out = token_num + BB;                        // [B,T1]
    float* cif_peak   = alphas_out + (size_t)BB * T1;          // [B,T1]

    float* cur       = (float*)d_ws;                           // [B,T1]
    float* rem       = cur + (size_t)BB * T1;                  // [B,T1]
    int*   fire_time = (int*)(rem + (size_t)BB * T1);          // [B,T1]
    int*   nfired    = fire_time + (size_t)BB * T1;            // [B]

    alpha_kernel<<<(BB * TT) / 4, 256, 0, stream>>>(hidden, w, bias, alphas_out);
    scan_kernel<<<BB, 128, 0, stream>>>(alphas_out, token_num, cif_peak,
                                        cur, rem, fire_time, nfired);
    fill_kernel<<<BB * T1, 128, 0, stream>>>(hidden, cur, rem, fire_time, nfired, ae);
}

// Round 2
// 55.591 us; speedup vs baseline: 2.0587x; 2.0587x over previous
//
#include <hip/hip_runtime.h>
#include <math.h>

#define BB 16
#define TT 1024
#define T1 1025
#define DD 512

// ---------------- Kernel 1: alphas = sigmoid(hidden @ w + b) ----------------
// one 64-lane wave per (b,t) row; 4 waves per 256-thread block
__global__ __launch_bounds__(256) void alpha_kernel(
    const float* __restrict__ hidden,   // [B, T, D]
    const float* __restrict__ w,        // [D]
    const float* __restrict__ bias,     // [1]
    float* __restrict__ alphas_out)     // [B, T1]  (t < T written here)
{
    int row  = blockIdx.x * 4 + (threadIdx.x >> 6);   // 0 .. B*T-1
    int lane = threadIdx.x & 63;
    const float* h = hidden + (size_t)row * DD;
    float4 x0 = *(const float4*)(h + lane * 4);
    float4 x1 = *(const float4*)(h + 256 + lane * 4);
    float4 w0 = *(const float4*)(w + lane * 4);
    float4 w1 = *(const float4*)(w + 256 + lane * 4);
    float s = x0.x * w0.x + x0.y * w0.y + x0.z * w0.z + x0.w * w0.w
            + x1.x * w1.x + x1.y * w1.y + x1.z * w1.z + x1.w * w1.w;
    #pragma unroll
    for (int off = 32; off > 0; off >>= 1) s += __shfl_down(s, off, 64);
    if (lane == 0) {
        float x = s + bias[0];
        float sig = 1.0f / (1.0f + expf(-x));
        int b = row >> 10;       // / TT
        int t = row & 1023;      // % TT
        alphas_out[b * T1 + t] = sig;
    }
}

// ---------------- Kernel 2: sequential CIF scalar scan (per batch) ----------
// 1 block per batch, 64 threads. Lane 0 runs the branchless dependency chain
// entirely out of LDS; everything else (token_num reduce, fire compaction,
// coalesced writeout) is wave-parallel.
__global__ __launch_bounds__(64) void scan_kernel(
    float* __restrict__ alphas_out,   // [B, T1]; tail col written here
    float* __restrict__ token_num,    // [B]
    float* __restrict__ cif_peak,     // [B, T1]
    float* __restrict__ cur,          // ws [B, T1]
    int*   __restrict__ fire_time,    // ws [B, T1]
    int*   __restrict__ nfired)       // ws [B]
{
    int b    = blockIdx.x;
    int lane = threadIdx.x;           // 0..63

    __shared__ float a_sh[TT + 8];    // zero-padded so prefetch never branches
    __shared__ float peak_sh[T1];
    __shared__ float cur_sh[T1];

    // stage alphas (coalesced)
    for (int t = lane; t < TT; t += 64) a_sh[t] = alphas_out[b * T1 + t];
    if (lane < 8) a_sh[TT + lane] = 0.0f;     // pad
    __syncthreads();

    // token_num = floor(sum(alphas)) — wave-parallel, off the serial chain
    double s = 0.0;
    for (int t = lane; t < TT; t += 64) s += (double)a_sh[t];
    #pragma unroll
    for (int off = 32; off > 0; off >>= 1) s += __shfl_down(s, off, 64);
    if (lane == 0) {
        token_num[b] = (float)floor(s);
        alphas_out[b * T1 + TT] = 0.0f;       // tail column of alphas output
    }

    // serial branchless chain on lane 0, software-pipelined 8-step chunks
    if (lane == 0) {
        float integrate = 0.0f;
        const float4* a4 = (const float4*)a_sh;
        float4 A0 = a4[0], A1 = a4[1];

#define STEP(AV, T) {                          \
        float dist = 1.0f - integrate;         \
        float ni   = integrate + (AV);         \
        bool fire  = ni >= 1.0f;               \
        peak_sh[T] = ni;                       \
        cur_sh[T]  = fire ? dist : (AV);       \
        integrate  = fire ? ni - 1.0f : ni;    \
    }

        for (int c = 0; c < 128; ++c) {
            float4 N0 = a4[2 * c + 2];         // prefetch next chunk (padded)
            float4 N1 = a4[2 * c + 3];
            int t0 = c * 8;
            STEP(A0.x, t0 + 0); STEP(A0.y, t0 + 1);
            STEP(A0.z, t0 + 2); STEP(A0.w, t0 + 3);
            STEP(A1.x, t0 + 4); STEP(A1.y, t0 + 5);
            STEP(A1.z, t0 + 6); STEP(A1.w, t0 + 7);
            A0 = N0; A1 = N1;
        }
        STEP(0.0f, TT);                        // appended tail step (alpha = 0)
#undef STEP
    }
    __syncthreads();

    // coalesced writeout of peaks / curs
    for (int t = lane; t < T1; t += 64) {
        cif_peak[b * T1 + t] = peak_sh[t];
        cur[b * T1 + t]      = cur_sh[t];
    }

    // fire-time compaction: fire flag == (peak >= 1.0f)
    int cnt = 0;
    int* ft_b = fire_time + b * T1;
    for (int base = 0; base < T1; base += 64) {
        int t = base + lane;
        bool f = (t < T1) && (peak_sh[t] >= 1.0f);
        unsigned long long m = __ballot(f);
        int pos = cnt + __popcll(m & ((1ull << lane) - 1ull));
        if (f) ft_b[pos] = t;
        cnt += __popcll(m);
    }
    if (lane == 0) nfired[b] = cnt;
}

// ---------------- Kernel 3: segmented weighted sums -> packed frames --------
// one block per (b, j) output row; 128 threads x float4 = 512 floats
__global__ __launch_bounds__(128) void fill_kernel(
    const float* __restrict__ hidden,     // [B, T, D]
    const float* __restrict__ alphas,     // [B, T1] (output buffer)
    const float* __restrict__ cur,        // ws [B, T1]
    const int*   __restrict__ fire_time,  // ws [B, T1]
    const int*   __restrict__ nfired,     // ws [B]
    float* __restrict__ ae)               // [B, T1, D]
{
    int idx = blockIdx.x;
    int b = idx / T1;
    int j = idx % T1;
    int d = threadIdx.x * 4;
    float4* out4 = (float4*)(ae + ((size_t)b * T1 + j) * DD + d);

    int nf = nfired[b];
    if (j >= nf) {                        // unfired slot: zeros
        *out4 = make_float4(0.f, 0.f, 0.f, 0.f);
        return;
    }
    const int*   ft_b  = fire_time + b * T1;
    const float* cur_b = cur + b * T1;
    const float* hb    = hidden + (size_t)b * TT * DD + d;

    int e = ft_b[j];                      // fire time of this token (<= T-1)
    float4 acc = make_float4(0.f, 0.f, 0.f, 0.f);
    int t0;
    if (j > 0) {
        int s = ft_b[j - 1];
        float r = alphas[b * T1 + s] - cur_b[s];   // remainds = alpha - cur (exact)
        float4 h = *(const float4*)(hb + (size_t)s * DD);
        acc.x = r * h.x; acc.y = r * h.y; acc.z = r * h.z; acc.w = r * h.w;
        t0 = s + 1;
    } else {
        t0 = 0;
    }
    for (int t = t0; t <= e; ++t) {       // uniform bounds per block -> no divergence
        float c = cur_b[t];
        float4 h = *(const float4*)(hb + (size_t)t * DD);
        acc.x += c * h.x; acc.y += c * h.y; acc.z += c * h.z; acc.w += c * h.w;
    }
    *out4 = acc;
}

extern "C" void kernel_launch(void* const* d_in, const int* in_sizes, int n_in,
                              void* d_out, int out_size, void* d_ws, size_t ws_size,
                              hipStream_t stream) {
    const float* hidden = (const float*)d_in[0];
    const float* w      = (const float*)d_in[1];
    const float* bias   = (const float*)d_in[2];

    float* out        = (float*)d_out;
    float* ae         = out;                                   // [B,T1,D]
    float* token_num  = out + (size_t)BB * T1 * DD;            // [B]
    float* alphas_out = token_num + BB;                        // [B,T1]
    float* cif_peak   = alphas_out + (size_t)BB * T1;          // [B,T1]

    float* cur       = (float*)d_ws;                           // [B,T1]
    int*   fire_time = (int*)(cur + (size_t)BB * T1);          // [B,T1]
    int*   nfired    = fire_time + (size_t)BB * T1;            // [B]

    alpha_kernel<<<(BB * TT) / 4, 256, 0, stream>>>(hidden, w, bias, alphas_out);
    scan_kernel<<<BB, 64, 0, stream>>>(alphas_out, token_num, cif_peak,
                                       cur, fire_time, nfired);
    fill_kernel<<<BB * T1, 128, 0, stream>>>(hidden, alphas_out, cur,
                                             fire_time, nfired, ae);
}

// Round 3
// 50.139 us; speedup vs baseline: 2.2826x; 1.1087x over previous
//
#include <hip/hip_runtime.h>
#include <math.h>

#define BB 16
#define TT 1024
#define T1 1025
#define DD 512

// ---------------- Kernel 1: alphas = sigmoid(hidden @ w + b) ----------------
// one 64-lane wave per (b,t) row; 4 waves per 256-thread block
__global__ __launch_bounds__(256) void alpha_kernel(
    const float* __restrict__ hidden,   // [B, T, D]
    const float* __restrict__ w,        // [D]
    const float* __restrict__ bias,     // [1]
    float* __restrict__ alphas_out)     // [B, T1]  (t < T written here)
{
    int row  = blockIdx.x * 4 + (threadIdx.x >> 6);   // 0 .. B*T-1
    int lane = threadIdx.x & 63;
    const float* h = hidden + (size_t)row * DD;
    float4 x0 = *(const float4*)(h + lane * 4);
    float4 x1 = *(const float4*)(h + 256 + lane * 4);
    float4 w0 = *(const float4*)(w + lane * 4);
    float4 w1 = *(const float4*)(w + 256 + lane * 4);
    float s = x0.x * w0.x + x0.y * w0.y + x0.z * w0.z + x0.w * w0.w
            + x1.x * w1.x + x1.y * w1.y + x1.z * w1.z + x1.w * w1.w;
    #pragma unroll
    for (int off = 32; off > 0; off >>= 1) s += __shfl_down(s, off, 64);
    if (lane == 0) {
        float x = s + bias[0];
        float sig = 1.0f / (1.0f + expf(-x));
        int b = row >> 10;       // / TT
        int t = row & 1023;      // % TT
        alphas_out[b * T1 + t] = sig;
    }
}

// ---------------- Kernel 2: sequential CIF scalar scan (per batch) ----------
// 128 threads. Wave0/lane0 runs the minimal serial chain (only `peak` is
// produced; cur/rem/fire are exactly reconstructible from peak+alpha since
// peak-1.0f is exact for peak in [1,2)). Wave1 concurrently computes
// token_num. Then coalesced writeout + ballot compaction of fire times.
__global__ __launch_bounds__(128) void scan_kernel(
    float* __restrict__ alphas_out,   // [B, T1]; tail col written here
    float* __restrict__ token_num,    // [B]
    float* __restrict__ cif_peak,     // [B, T1]
    int*   __restrict__ fire_time,    // ws [B, T1]
    int*   __restrict__ nfired)       // ws [B]
{
    int b   = blockIdx.x;
    int tid = threadIdx.x;            // 0..127

    __shared__ float a_sh[TT + 8];    // zero-padded so prefetch never branches
    __shared__ float peak_sh[T1 + 3];

    // stage alphas (coalesced)
    for (int t = tid; t < TT; t += 128) a_sh[t] = alphas_out[b * T1 + t];
    if (tid < 8) a_sh[TT + tid] = 0.0f;     // pad
    __syncthreads();

    if (tid == 0) {
        // ---- minimal serial chain: 3 ops/step, peaks batched to b128 writes
        float integrate = 0.0f;
        const float4* a4 = (const float4*)a_sh;
        float4* p4 = (float4*)peak_sh;
        float4 A0 = a4[0], A1 = a4[1];

#define STEP(AV, PV) {                                   \
        float ni = integrate + (AV);                     \
        (PV) = ni;                                       \
        integrate = (ni >= 1.0f) ? ni - 1.0f : ni;       \
    }
        for (int c = 0; c < 128; ++c) {
            float4 N0 = a4[2 * c + 2];    // prefetch next chunk (padded)
            float4 N1 = a4[2 * c + 3];
            float4 P0, P1;
            STEP(A0.x, P0.x) STEP(A0.y, P0.y) STEP(A0.z, P0.z) STEP(A0.w, P0.w)
            STEP(A1.x, P1.x) STEP(A1.y, P1.y) STEP(A1.z, P1.z) STEP(A1.w, P1.w)
            p4[2 * c]     = P0;
            p4[2 * c + 1] = P1;
            A0 = N0; A1 = N1;
        }
#undef STEP
        // tail step: alpha = 0 -> ni == integrate (< 1, no fire)
        peak_sh[TT] = integrate;
    } else if (tid >= 64) {
        // ---- wave1: token_num = floor(sum alphas), concurrent with chain
        int lane = tid - 64;
        double s = 0.0;
        for (int t = lane; t < TT; t += 64) s += (double)a_sh[t];
        #pragma unroll
        for (int off = 32; off > 0; off >>= 1) s += __shfl_down(s, off, 64);
        if (lane == 0) {
            token_num[b] = (float)floor(s);
            alphas_out[b * T1 + TT] = 0.0f;       // tail column of alphas output
        }
    }
    __syncthreads();

    // coalesced writeout of peaks
    for (int t = tid; t < T1; t += 128) cif_peak[b * T1 + t] = peak_sh[t];

    // fire-time compaction on wave0: fire flag == (peak >= 1.0f)
    if (tid < 64) {
        int cnt = 0;
        int* ft_b = fire_time + b * T1;
        for (int base = 0; base < T1; base += 64) {
            int t = base + tid;
            bool f = (t < T1) && (peak_sh[t] >= 1.0f);
            unsigned long long m = __ballot(f);
            int pos = cnt + __popcll(m & ((1ull << tid) - 1ull));
            if (f) ft_b[pos] = t;
            cnt += __popcll(m);
        }
        if (tid == 0) nfired[b] = cnt;
    }
}

// ---------------- Kernel 3: segmented weighted sums -> packed frames --------
// one block per (b, j) output row; 128 threads x float4 = 512 floats.
// cur/rem reconstructed exactly from (peak, alpha):
//   integrate_prev(t) = peak[t-1] >= 1 ? peak[t-1]-1 : peak[t-1]   (exact)
//   cur(fire t)       = 1 - integrate_prev(t)
//   interior cur(t)   = alpha[t]
//   rem(s)            = alpha[s] - cur(s)
__global__ __launch_bounds__(128) void fill_kernel(
    const float* __restrict__ hidden,     // [B, T, D]
    const float* __restrict__ alphas,     // [B, T1] (output buffer)
    const float* __restrict__ peak,       // [B, T1] (cif_peak output)
    const int*   __restrict__ fire_time,  // ws [B, T1]
    const int*   __restrict__ nfired,     // ws [B]
    float* __restrict__ ae)               // [B, T1, D]
{
    int idx = blockIdx.x;
    int b = idx / T1;
    int j = idx % T1;
    int d = threadIdx.x * 4;
    float4* out4 = (float4*)(ae + ((size_t)b * T1 + j) * DD + d);

    int nf = nfired[b];
    if (j >= nf) {                        // unfired slot: zeros
        *out4 = make_float4(0.f, 0.f, 0.f, 0.f);
        return;
    }
    const int*   ft_b = fire_time + b * T1;
    const float* a_b  = alphas + b * T1;
    const float* pk_b = peak + b * T1;
    const float* hb   = hidden + (size_t)b * TT * DD + d;

    int e = ft_b[j];                      // fire time of this token (>= 1)
    float4 acc = make_float4(0.f, 0.f, 0.f, 0.f);
    int t0;
    if (j > 0) {
        int s = ft_b[j - 1];              // previous fire time (>= 1)
        float ps   = (s > 0) ? pk_b[s - 1] : 0.0f;
        float ips  = (ps >= 1.0f) ? ps - 1.0f : ps;   // integrate before step s
        float curs = 1.0f - ips;                      // dist_completion at s
        float r    = a_b[s] - curs;                   // remainds at s
        float4 h = *(const float4*)(hb + (size_t)s * DD);
        acc.x = r * h.x; acc.y = r * h.y; acc.z = r * h.z; acc.w = r * h.w;
        t0 = s + 1;
    } else {
        t0 = 0;
    }
    for (int t = t0; t < e; ++t) {        // interior rows: cur = alpha
        float c = a_b[t];
        float4 h = *(const float4*)(hb + (size_t)t * DD);
        acc.x += c * h.x; acc.y += c * h.y; acc.z += c * h.z; acc.w += c * h.w;
    }
    {   // final row t = e (the fire): cur = 1 - integrate_prev(e)
        float pe  = (e > 0) ? pk_b[e - 1] : 0.0f;
        float ipe = (pe >= 1.0f) ? pe - 1.0f : pe;
        float ce  = 1.0f - ipe;
        float4 h = *(const float4*)(hb + (size_t)e * DD);
        acc.x += ce * h.x; acc.y += ce * h.y; acc.z += ce * h.z; acc.w += ce * h.w;
    }
    *out4 = acc;
}

extern "C" void kernel_launch(void* const* d_in, const int* in_sizes, int n_in,
                              void* d_out, int out_size, void* d_ws, size_t ws_size,
                              hipStream_t stream) {
    const float* hidden = (const float*)d_in[0];
    const float* w      = (const float*)d_in[1];
    const float* bias   = (const float*)d_in[2];

    float* out        = (float*)d_out;
    float* ae         = out;                                   // [B,T1,D]
    float* token_num  = out + (size_t)BB * T1 * DD;            // [B]
    float* alphas_out = token_num + BB;                        // [B,T1]
    float* cif_peak   = alphas_out + (size_t)BB * T1;          // [B,T1]

    int* fire_time = (int*)d_ws;                               // [B,T1]
    int* nfired    = fire_time + (size_t)BB * T1;              // [B]

    alpha_kernel<<<(BB * TT) / 4, 256, 0, stream>>>(hidden, w, bias, alphas_out);
    scan_kernel<<<BB, 128, 0, stream>>>(alphas_out, token_num, cif_peak,
                                        fire_time, nfired);
    fill_kernel<<<BB * T1, 128, 0, stream>>>(hidden, alphas_out, cif_peak,
                                             fire_time, nfired, ae);
}

// Round 4
// 38.680 us; speedup vs baseline: 2.9588x; 1.2962x over previous
//
#include <hip/hip_runtime.h>
#include <math.h>

#define BB 16
#define TT 1024
#define T1 1025
#define DD 512

__device__ __forceinline__ float fract_exact(float x) {
#if defined(__has_builtin)
#if __has_builtin(__builtin_amdgcn_fractf)
    return __builtin_amdgcn_fractf(x);     // v_fract_f32: x - floor(x), exact
#else
    return x - floorf(x);
#endif
#else
    return x - floorf(x);
#endif
}

// ---------------- Kernel 1: alphas = sigmoid(hidden @ w + b) ----------------
// one 64-lane wave per (b,t) row; 4 waves per 256-thread block
__global__ __launch_bounds__(256) void alpha_kernel(
    const float* __restrict__ hidden,   // [B, T, D]
    const float* __restrict__ w,        // [D]
    const float* __restrict__ bias,     // [1]
    float* __restrict__ alphas_out)     // [B, T1]  (t < T written here)
{
    int row  = blockIdx.x * 4 + (threadIdx.x >> 6);   // 0 .. B*T-1
    int lane = threadIdx.x & 63;
    const float* h = hidden + (size_t)row * DD;
    float4 x0 = *(const float4*)(h + lane * 4);
    float4 x1 = *(const float4*)(h + 256 + lane * 4);
    float4 w0 = *(const float4*)(w + lane * 4);
    float4 w1 = *(const float4*)(w + 256 + lane * 4);
    float s = x0.x * w0.x + x0.y * w0.y + x0.z * w0.z + x0.w * w0.w
            + x1.x * w1.x + x1.y * w1.y + x1.z * w1.z + x1.w * w1.w;
    #pragma unroll
    for (int off = 32; off > 0; off >>= 1) s += __shfl_down(s, off, 64);
    if (lane == 0) {
        float x = s + bias[0];
        float sig = 1.0f / (1.0f + expf(-x));
        int b = row >> 10;       // / TT
        int t = row & 1023;      // % TT
        alphas_out[b * T1 + t] = sig;
    }
}

// ---------------- Kernel 2: sequential CIF scalar scan (per batch) ----------
// 128 threads. Wave0/lane0 runs the minimal serial chain:
//   ni = integrate + a;  peak[t] = ni;  integrate = fract(ni)   (bit-exact)
// 16-step chunks, LDS prefetch issued 2 chunks ahead. Wave1 concurrently
// computes token_num. Then coalesced writeout + ballot fire compaction.
__global__ __launch_bounds__(128) void scan_kernel(
    float* __restrict__ alphas_out,   // [B, T1]; tail col written here
    float* __restrict__ token_num,    // [B]
    float* __restrict__ cif_peak,     // [B, T1]
    int*   __restrict__ fire_time,    // ws [B, T1]
    int*   __restrict__ nfired)       // ws [B]
{
    int b   = blockIdx.x;
    int tid = threadIdx.x;            // 0..127

    __shared__ float a_sh[TT + 32];   // zero-padded so prefetch never branches
    __shared__ float peak_sh[T1 + 3];

    // stage alphas (coalesced)
    for (int t = tid; t < TT; t += 128) a_sh[t] = alphas_out[b * T1 + t];
    if (tid < 32) a_sh[TT + tid] = 0.0f;     // pad (2 chunks)
    __syncthreads();

    if (tid == 0) {
        float integrate = 0.0f;
        const float4* a4 = (const float4*)a_sh;
        float4* p4 = (float4*)peak_sh;

        // 2-chunk-deep register pipeline, 16 steps (4x float4) per chunk
        float4 C0 = a4[0], C1 = a4[1], C2 = a4[2], C3 = a4[3];
        float4 D0 = a4[4], D1 = a4[5], D2 = a4[6], D3 = a4[7];

#define STEP(AV, PV) {                       \
        float ni = integrate + (AV);         \
        (PV) = ni;                           \
        integrate = fract_exact(ni);         \
    }
        for (int c = 0; c < 64; ++c) {
            // prefetch chunk c+2 (padded region keeps this in-bounds)
            float4 N0 = a4[(c + 2) * 4 + 0];
            float4 N1 = a4[(c + 2) * 4 + 1];
            float4 N2 = a4[(c + 2) * 4 + 2];
            float4 N3 = a4[(c + 2) * 4 + 3];
            float4 P0, P1, P2, P3;
            STEP(C0.x, P0.x) STEP(C0.y, P0.y) STEP(C0.z, P0.z) STEP(C0.w, P0.w)
            STEP(C1.x, P1.x) STEP(C1.y, P1.y) STEP(C1.z, P1.z) STEP(C1.w, P1.w)
            STEP(C2.x, P2.x) STEP(C2.y, P2.y) STEP(C2.z, P2.z) STEP(C2.w, P2.w)
            STEP(C3.x, P3.x) STEP(C3.y, P3.y) STEP(C3.z, P3.z) STEP(C3.w, P3.w)
            p4[c * 4 + 0] = P0;
            p4[c * 4 + 1] = P1;
            p4[c * 4 + 2] = P2;
            p4[c * 4 + 3] = P3;
            C0 = D0; C1 = D1; C2 = D2; C3 = D3;
            D0 = N0; D1 = N1; D2 = N2; D3 = N3;
        }
#undef STEP
        // tail step: alpha = 0 -> ni == integrate (< 1, no fire)
        peak_sh[TT] = integrate;
    } else if (tid >= 64) {
        // ---- wave1: token_num = floor(sum alphas), concurrent with chain
        int lane = tid - 64;
        double s = 0.0;
        for (int t = lane; t < TT; t += 64) s += (double)a_sh[t];
        #pragma unroll
        for (int off = 32; off > 0; off >>= 1) s += __shfl_down(s, off, 64);
        if (lane == 0) {
            token_num[b] = (float)floor(s);
            alphas_out[b * T1 + TT] = 0.0f;       // tail column of alphas output
        }
    }
    __syncthreads();

    // coalesced writeout of peaks
    for (int t = tid; t < T1; t += 128) cif_peak[b * T1 + t] = peak_sh[t];

    // fire-time compaction on wave0: fire flag == (peak >= 1.0f)
    if (tid < 64) {
        int cnt = 0;
        int* ft_b = fire_time + b * T1;
        for (int base = 0; base < T1; base += 64) {
            int t = base + tid;
            bool f = (t < T1) && (peak_sh[t] >= 1.0f);
            unsigned long long m = __ballot(f);
            int pos = cnt + __popcll(m & ((1ull << tid) - 1ull));
            if (f) ft_b[pos] = t;
            cnt += __popcll(m);
        }
        if (tid == 0) nfired[b] = cnt;
    }
}

// ---------------- Kernel 3: segmented weighted sums -> packed frames --------
// one block per (b, j) output row; 128 threads x float4 = 512 floats.
// cur/rem reconstructed exactly from (peak, alpha):
//   integrate_prev(t) = peak[t-1] >= 1 ? peak[t-1]-1 : peak[t-1]   (exact)
//   cur(fire t)       = 1 - integrate_prev(t)
//   interior cur(t)   = alpha[t]
//   rem(s)            = alpha[s] - cur(s)
__global__ __launch_bounds__(128) void fill_kernel(
    const float* __restrict__ hidden,     // [B, T, D]
    const float* __restrict__ alphas,     // [B, T1] (output buffer)
    const float* __restrict__ peak,       // [B, T1] (cif_peak output)
    const int*   __restrict__ fire_time,  // ws [B, T1]
    const int*   __restrict__ nfired,     // ws [B]
    float* __restrict__ ae)               // [B, T1, D]
{
    int idx = blockIdx.x;
    int b = idx / T1;
    int j = idx % T1;
    int d = threadIdx.x * 4;
    float4* out4 = (float4*)(ae + ((size_t)b * T1 + j) * DD + d);

    int nf = nfired[b];
    if (j >= nf) {                        // unfired slot: zeros
        *out4 = make_float4(0.f, 0.f, 0.f, 0.f);
        return;
    }
    const int*   ft_b = fire_time + b * T1;
    const float* a_b  = alphas + b * T1;
    const float* pk_b = peak + b * T1;
    const float* hb   = hidden + (size_t)b * TT * DD + d;

    int e = ft_b[j];                      // fire time of this token
    float4 acc = make_float4(0.f, 0.f, 0.f, 0.f);
    int t0;
    if (j > 0) {
        int s = ft_b[j - 1];              // previous fire time
        float ps   = (s > 0) ? pk_b[s - 1] : 0.0f;
        float ips  = (ps >= 1.0f) ? ps - 1.0f : ps;   // integrate before step s
        float curs = 1.0f - ips;                      // dist_completion at s
        float r    = a_b[s] - curs;                   // remainds at s
        float4 h = *(const float4*)(hb + (size_t)s * DD);
        acc.x = r * h.x; acc.y = r * h.y; acc.z = r * h.z; acc.w = r * h.w;
        t0 = s + 1;
    } else {
        t0 = 0;
    }
    for (int t = t0; t < e; ++t) {        // interior rows: cur = alpha
        float c = a_b[t];
        float4 h = *(const float4*)(hb + (size_t)t * DD);
        acc.x += c * h.x; acc.y += c * h.y; acc.z += c * h.z; acc.w += c * h.w;
    }
    {   // final row t = e (the fire): cur = 1 - integrate_prev(e)
        float pe  = (e > 0) ? pk_b[e - 1] : 0.0f;
        float ipe = (pe >= 1.0f) ? pe - 1.0f : pe;
        float ce  = 1.0f - ipe;
        float4 h = *(const float4*)(hb + (size_t)e * DD);
        acc.x += ce * h.x; acc.y += ce * h.y; acc.z += ce * h.z; acc.w += ce * h.w;
    }
    *out4 = acc;
}

extern "C" void kernel_launch(void* const* d_in, const int* in_sizes, int n_in,
                              void* d_out, int out_size, void* d_ws, size_t ws_size,
                              hipStream_t stream) {
    const float* hidden = (const float*)d_in[0];
    const float* w      = (const float*)d_in[1];
    const float* bias   = (const float*)d_in[2];

    float* out        = (float*)d_out;
    float* ae         = out;                                   // [B,T1,D]
    float* token_num  = out + (size_t)BB * T1 * DD;            // [B]
    float* alphas_out = token_num + BB;                        // [B,T1]
    float* cif_peak   = alphas_out + (size_t)BB * T1;          // [B,T1]

    int* fire_time = (int*)d_ws;                               // [B,T1]
    int* nfired    = fire_time + (size_t)BB * T1;              // [B]

    alpha_kernel<<<(BB * TT) / 4, 256, 0, stream>>>(hidden, w, bias, alphas_out);
    scan_kernel<<<BB, 128, 0, stream>>>(alphas_out, token_num, cif_peak,
                                        fire_time, nfired);
    fill_kernel<<<BB * T1, 128, 0, stream>>>(hidden, alphas_out, cif_peak,
                                             fire_time, nfired, ae);
}